// Round 10
// baseline (207.265 us; speedup 1.0000x reference)
//
#include <hip/hip_runtime.h>

typedef __attribute__((ext_vector_type(8))) short bf16x8;
typedef __attribute__((ext_vector_type(4))) float f32x4;

union FragU { uint4 q; bf16x8 h; };

__device__ __forceinline__ unsigned short f2bf(float f) {
  unsigned u = __float_as_uint(f);
  u += 0x7FFFu + ((u >> 16) & 1u);   // RNE
  return (unsigned short)(u >> 16);
}
__device__ __forceinline__ unsigned pack2(float lo, float hi) {
  return (unsigned)f2bf(lo) | ((unsigned)f2bf(hi) << 16);
}

// ===========================================================================
// DIAGNOSTIC ROUND: r8 kernels verbatim, each body wrapped in an idempotent
// repeat loop (kX x32, kA x16, kB x32) so every dispatch exceeds the ~39us
// fill dispatches and surfaces in rocprof top-5 with real counters.
// Same stores every rep -> output identical -> still passes validation.
// ===========================================================================

#define REP_KX 32
#define REP_KA 16
#define REP_KB 32

__global__ __launch_bounds__(256) void kX(
    const float* __restrict__ x, const float* __restrict__ W1,
    const float* __restrict__ W2, uint4* __restrict__ xbf,
    uint4* __restrict__ w1f, uint4* __restrict__ w2f)
{
  for (int rep = 0; rep < REP_KX; ++rep) {
    asm volatile("" ::: "memory");   // keep loads inside the rep loop
    const int u = blockIdx.x * 256 + threadIdx.x;
    if (u < 131072) {            // x frags: 16b x 16t x 8c x 64l
      const int l = u & 63, c = (u >> 6) & 7, t = (u >> 9) & 15, b = u >> 13;
      const int fr = l & 15, fq = l >> 4;
      const float* p = x + (size_t)((b * 16 + t) * 16 + fr) * 256 + c * 32 + fq * 8;
      float4 va = *(const float4*)p;
      float4 vb = *(const float4*)(p + 4);
      xbf[u] = make_uint4(pack2(va.x, va.y), pack2(va.z, va.w),
                          pack2(vb.x, vb.y), pack2(vb.z, vb.w));
    } else if (u < 139264) {     // W1 frags: 16hc x 8c x 64l
      const int u2 = u - 131072;
      const int l = u2 & 63, c = (u2 >> 6) & 7, hc = u2 >> 9;
      const int fr = l & 15, fq = l >> 4;
      const float* p = W1 + (size_t)((fr >= 8) ? 256 : 0) * 128 +
                       (size_t)(c * 32 + fq * 8) * 128 + hc * 8 + (fr & 7);
      float v[8];
#pragma unroll
      for (int j = 0; j < 8; ++j) v[j] = p[(size_t)j * 128];
      w1f[u2] = make_uint4(pack2(v[0], v[1]), pack2(v[2], v[3]),
                           pack2(v[4], v[5]), pack2(v[6], v[7]));
    } else if (u < 143360) {     // W2 frags: 16dg x 4c x 64l
      const int u3 = u - 139264;
      const int l = u3 & 63, c = (u3 >> 6) & 3, dg = u3 >> 8;
      const int fr = l & 15, fq = l >> 4;
      const float* p = W2 + (size_t)(c * 32 + fq * 8) * 256 + dg * 16 + fr;
      float v[8];
#pragma unroll
      for (int j = 0; j < 8; ++j) v[j] = p[(size_t)j * 256];
      w2f[u3] = make_uint4(pack2(v[0], v[1]), pack2(v[2], v[3]),
                           pack2(v[4], v[5]), pack2(v[6], v[7]));
    }
  }
}

__global__ __launch_bounds__(1024) void kA(
    const uint4* __restrict__ xbf, const uint4* __restrict__ w1f,
    const float* __restrict__ b1, uint4* __restrict__ mf)
{
  __shared__ float Cs[8][260];
  __shared__ float As[8][260];
  __shared__ float PB[8][260];

  const int tid = threadIdx.x, lane = tid & 63, wv = tid >> 6;
  const int b = blockIdx.x, hc = blockIdx.y;
  const int fr = lane & 15, fq = lane >> 4;

  for (int rep = 0; rep < REP_KA; ++rep) {
    asm volatile("" ::: "memory");   // keep loads inside the rep loop

    FragU afr[8];
#pragma unroll
    for (int c = 0; c < 8; ++c) afr[c].q = w1f[(hc * 8 + c) * 64 + lane];

    float b1v[4];
#pragma unroll
    for (int g = 0; g < 4; ++g)
      b1v[g] = (fq >= 2) ? b1[hc * 8 + (fq - 2) * 4 + g] : 0.f;

    {  // phase 1: MFMA, wave = m-tile
      const int t = wv;
      f32x4 acc = {0.f, 0.f, 0.f, 0.f};
#pragma unroll
      for (int c = 0; c < 8; ++c) {
        FragU bfr;
        bfr.q = xbf[((size_t)(b * 16 + t) * 8 + c) * 64 + lane];
        acc = __builtin_amdgcn_mfma_f32_16x16x32_bf16(afr[c].h, bfr.h, acc, 0, 0, 0);
      }
      const int m = t * 16 + fr;
      if (fq < 2) {
#pragma unroll
        for (int g = 0; g < 4; ++g) As[fq * 4 + g][m] = acc[g];
      } else {
#pragma unroll
        for (int g = 0; g < 4; ++g) Cs[(fq - 2) * 4 + g][m] = acc[g] + b1v[g];
      }
    }
    __syncthreads();

    const int hp = wv & 7, kh = wv >> 3;
    const float a0 = As[hp][lane],       a1 = As[hp][64 + lane];
    const float a2 = As[hp][128 + lane], a3 = As[hp][192 + lane];

    float sumC = 0.f;
    if (kh == 0) {
      float4 s4 = *(const float4*)&Cs[hp][lane * 4];
      sumC = (s4.x + s4.y) + (s4.z + s4.w);
#pragma unroll
      for (int off = 32; off >= 1; off >>= 1) sumC += __shfl_xor(sumC, off, 64);
    }

    float s0a = 0.f, s0b = 0.f, s1a = 0.f, s1b = 0.f;
    float s2a = 0.f, s2b = 0.f, s3a = 0.f, s3b = 0.f;
    const int u0 = kh * 32;
#pragma unroll 8
    for (int u = 0; u < 32; ++u) {
      float4 c = *(const float4*)&Cs[hp][(u0 + u) * 4];  // uniform -> broadcast
      s0a += fabsf(a0 + c.x); s0b += fabsf(a0 + c.y);
      s0a += fabsf(a0 + c.z); s0b += fabsf(a0 + c.w);
      s1a += fabsf(a1 + c.x); s1b += fabsf(a1 + c.y);
      s1a += fabsf(a1 + c.z); s1b += fabsf(a1 + c.w);
      s2a += fabsf(a2 + c.x); s2b += fabsf(a2 + c.y);
      s2a += fabsf(a2 + c.z); s2b += fabsf(a2 + c.w);
      s3a += fabsf(a3 + c.x); s3b += fabsf(a3 + c.y);
      s3a += fabsf(a3 + c.z); s3b += fabsf(a3 + c.w);
    }

    if (kh == 1) {
      PB[hp][lane]       = s0a + s0b;
      PB[hp][64 + lane]  = s1a + s1b;
      PB[hp][128 + lane] = s2a + s2b;
      PB[hp][192 + lane] = s3a + s3b;
    }
    __syncthreads();

    if (kh == 0) {
      As[hp][lane]       = (256.f * a0 + sumC + (s0a + s0b) + PB[hp][lane])       * (1.f / 512.f);
      As[hp][64 + lane]  = (256.f * a1 + sumC + (s1a + s1b) + PB[hp][64 + lane])  * (1.f / 512.f);
      As[hp][128 + lane] = (256.f * a2 + sumC + (s2a + s2b) + PB[hp][128 + lane]) * (1.f / 512.f);
      As[hp][192 + lane] = (256.f * a3 + sumC + (s3a + s3b) + PB[hp][192 + lane]) * (1.f / 512.f);
    }
    __syncthreads();

    if (tid < 256) {  // phase 3: pack into kB fragment layout
      const int fr2 = tid & 15, T = tid >> 4;
      uint4 o = make_uint4(pack2(As[0][tid], As[1][tid]), pack2(As[2][tid], As[3][tid]),
                           pack2(As[4][tid], As[5][tid]), pack2(As[6][tid], As[7][tid]));
      mf[((size_t)(b * 16 + T) * 4 + (hc >> 2)) * 64 + (hc & 3) * 16 + fr2] = o;
    }
    __syncthreads();  // protect As/Cs reuse across reps
  }
}

__global__ __launch_bounds__(256) void kB(
    const uint4* __restrict__ mf, const uint4* __restrict__ w2f,
    const float* __restrict__ b2, const float* __restrict__ x,
    float* __restrict__ out)
{
  const int tid = threadIdx.x, lane = tid & 63, wu = tid >> 6;
  const int mt = blockIdx.x;
  const int dg = blockIdx.y * 4 + wu;
  const int fr = lane & 15, fq = lane >> 4;

  for (int rep = 0; rep < REP_KB; ++rep) {
    asm volatile("" ::: "memory");   // keep loads inside the rep loop
    f32x4 acc = {0.f, 0.f, 0.f, 0.f};
#pragma unroll
    for (int c = 0; c < 4; ++c) {
      FragU a, bb;
      a.q  = mf[((size_t)mt * 4 + c) * 64 + lane];
      bb.q = w2f[((size_t)dg * 4 + c) * 64 + lane];
      acc = __builtin_amdgcn_mfma_f32_16x16x32_bf16(a.h, bb.h, acc, 0, 0, 0);
    }
    const int d = dg * 16 + fr;
    const float bv = b2[d];
#pragma unroll
    for (int g = 0; g < 4; ++g) {
      const int m = mt * 16 + fq * 4 + g;
      const size_t o = (size_t)m * 256 + d;
      out[o] = acc[g] + bv + x[o];
    }
  }
}

extern "C" void kernel_launch(void* const* d_in, const int* in_sizes, int n_in,
                              void* d_out, int out_size, void* d_ws, size_t ws_size,
                              hipStream_t stream) {
  const float* x  = (const float*)d_in[0];
  const float* W1 = (const float*)d_in[1];
  const float* b1 = (const float*)d_in[2];
  const float* W2 = (const float*)d_in[3];
  const float* b2 = (const float*)d_in[4];
  float* out = (float*)d_out;

  char* ws = (char*)d_ws;
  uint4* xbf = (uint4*)ws;                               // 131072 u = 2 MB
  uint4* w1f = (uint4*)(ws + (2u << 20));                // 8192 u = 128 KB
  uint4* w2f = (uint4*)(ws + (2u << 20) + (128u << 10)); // 4096 u = 64 KB
  uint4* mf  = (uint4*)(ws + (2u << 20) + (192u << 10)); // 65536 u = 1 MB

  kX<<<560, 256, 0, stream>>>(x, W1, W2, xbf, w1f, w2f);
  kA<<<dim3(16, 16), 1024, 0, stream>>>(xbf, w1f, b1, mf);
  kB<<<dim3(256, 4), 256, 0, stream>>>(mf, w2f, b2, x, out);
}

// Round 11
// 25.909 us; speedup vs baseline: 7.9997x; 7.9997x over previous
//
#include <hip/hip_runtime.h>

typedef __attribute__((ext_vector_type(8))) short bf16x8;
typedef __attribute__((ext_vector_type(4))) float f32x4;
typedef __attribute__((ext_vector_type(2))) float f32x2;

union FragU { uint4 q; bf16x8 h; };

// packed f32->2xbf16 convert (RNE), 1 VALU instr  [guide T12: gfx950-verified]
__device__ __forceinline__ unsigned cvt_pk(float lo, float hi) {
  unsigned r;
  asm("v_cvt_pk_bf16_f32 %0, %1, %2" : "=v"(r) : "v"(lo), "v"(hi));
  return r;
}

// ---------------------------------------------------------------------------
// kA: fused cast + GEMM1 h-slice + pairwise-mean.  Block (b, hc), 1024 thr
// = 16 waves (4/SIMD).  LDS: x[b] as swizzled bf16 (128 KB) + As/Cs/PB.
//   phase 0: stage x[b] f32->bf16 LDS (r7-proven swizzle), gather-cast 16
//            W1 cols to A-frags (r6-proven), all via cvt_pk.
//   phase 1: wave wv = m-tile wv: 8 MFMA -> As[8][m] (a), Cs[8][m] (c+b1).
//   phase 2: wave (hp, kh): R=4 rows x 128 k2; inner = v_pk_add_f32 (asm)
//            + fabsf-fold accumulate = 1.5 VALU/elem; partials via PB.
//   phase 3: pack mh into kB fragment layout (r8-verified mapping).
// Grid (16, 16) = 256 blocks, 1 block/CU (156 KB LDS).
// ---------------------------------------------------------------------------
__global__ __launch_bounds__(1024) void kA(
    const float* __restrict__ x, const float* __restrict__ W1,
    const float* __restrict__ b1, uint4* __restrict__ mf)
{
  __shared__ __align__(16) unsigned short xs[256 * 256];  // 128 KB, swizzled
  __shared__ float As[8][260];
  __shared__ float Cs[8][260];
  __shared__ float PB[8][260];

  const int tid = threadIdx.x, lane = tid & 63, wv = tid >> 6;  // wv 0..15
  const int b = blockIdx.x, hc = blockIdx.y;
  const int fr = lane & 15, fq = lane >> 4;

  // ---- phase 0a: stage x[b] (256x256 f32) -> bf16 LDS, 8B-unit XOR swizzle
#pragma unroll
  for (int i = 0; i < 16; ++i) {
    const int idx = i * 1024 + tid;
    const int row = idx >> 6, u = idx & 63;
    float4 v = *(const float4*)&x[(size_t)(b * 256 + row) * 256 + u * 4];
    uint2 hv = make_uint2(cvt_pk(v.x, v.y), cvt_pk(v.z, v.w));
    *(uint2*)&xs[row * 256 + (u ^ ((row & 7) << 1)) * 4] = hv;
  }

  // ---- phase 0b: A-frags from native W1 (16 n-cols: n<8 -> W1a, else W1b)
  const float* __restrict__ wp =
      W1 + (size_t)((fr >= 8) ? 256 : 0) * 128 + hc * 8 + (fr & 7);
  FragU afr[8];
#pragma unroll
  for (int c = 0; c < 8; ++c) {
    float v[8];
#pragma unroll
    for (int j = 0; j < 8; ++j) v[j] = wp[(size_t)(c * 32 + fq * 8 + j) * 128];
    afr[c].q = make_uint4(cvt_pk(v[0], v[1]), cvt_pk(v[2], v[3]),
                          cvt_pk(v[4], v[5]), cvt_pk(v[6], v[7]));
  }

  float b1v[4];
#pragma unroll
  for (int g = 0; g < 4; ++g)
    b1v[g] = (fq >= 2) ? b1[hc * 8 + (fq - 2) * 4 + g] : 0.f;

  __syncthreads();

  // ---- phase 1: MFMA, wave = m-tile; D row = n' (A dim), col = m
  {
    const int mrow = wv * 16 + fr;
    const int swz = (mrow & 7) << 1;
    f32x4 acc = {0.f, 0.f, 0.f, 0.f};
#pragma unroll
    for (int c = 0; c < 8; ++c) {
      const int pu = (c * 8 + fq * 2) ^ swz;
      bf16x8 bfr = *(const bf16x8*)&xs[mrow * 256 + pu * 4];
      acc = __builtin_amdgcn_mfma_f32_16x16x32_bf16(afr[c].h, bfr, acc, 0, 0, 0);
    }
    if (fq < 2) {
#pragma unroll
      for (int g = 0; g < 4; ++g) As[fq * 4 + g][mrow] = acc[g];
    } else {
#pragma unroll
      for (int g = 0; g < 4; ++g) Cs[(fq - 2) * 4 + g][mrow] = acc[g] + b1v[g];
    }
  }
  __syncthreads();

  // ---- phase 2: pairwise, wave = (hp, kh); c-row via broadcast ds_read_b128
  const int hp = wv & 7, kh = wv >> 3;
  const float a0 = As[hp][lane],       a1 = As[hp][64 + lane];
  const float a2 = As[hp][128 + lane], a3 = As[hp][192 + lane];

  float sumC = 0.f;
  if (kh == 0) {
    float4 s4 = *(const float4*)&Cs[hp][lane * 4];
    sumC = (s4.x + s4.y) + (s4.z + s4.w);
#pragma unroll
    for (int off = 32; off >= 1; off >>= 1) sumC += __shfl_xor(sumC, off, 64);
  }

  const f32x2 aa0 = {a0, a0}, aa1 = {a1, a1}, aa2 = {a2, a2}, aa3 = {a3, a3};
  float s0l = 0.f, s0h = 0.f, s1l = 0.f, s1h = 0.f;
  float s2l = 0.f, s2h = 0.f, s3l = 0.f, s3h = 0.f;
  const int u0 = kh * 32;

  // per 2 elems: 1 v_pk_add_f32 + 2 abs-folded v_add_f32 = 1.5 VALU/elem.
  // (sl accumulates c.x,c.z; sh accumulates c.y,c.w — same pairing as r8
  //  -> bitwise-identical sums)
#define PROW(aa, sl, sh)                                                   \
  {                                                                        \
    f32x2 t0, t1;                                                          \
    asm("v_pk_add_f32 %0, %1, %2" : "=v"(t0) : "v"(aa), "v"(c01));         \
    asm("v_pk_add_f32 %0, %1, %2" : "=v"(t1) : "v"(aa), "v"(c23));         \
    sl += __builtin_fabsf(t0.x); sh += __builtin_fabsf(t0.y);              \
    sl += __builtin_fabsf(t1.x); sh += __builtin_fabsf(t1.y);              \
  }

#pragma unroll 8
  for (int u = 0; u < 32; ++u) {
    float4 c4 = *(const float4*)&Cs[hp][(u0 + u) * 4];  // uniform -> broadcast
    f32x2 c01 = {c4.x, c4.y}, c23 = {c4.z, c4.w};
    PROW(aa0, s0l, s0h)
    PROW(aa1, s1l, s1h)
    PROW(aa2, s2l, s2h)
    PROW(aa3, s3l, s3h)
  }
#undef PROW

  if (kh == 1) {
    PB[hp][lane]       = s0l + s0h;
    PB[hp][64 + lane]  = s1l + s1h;
    PB[hp][128 + lane] = s2l + s2h;
    PB[hp][192 + lane] = s3l + s3h;
  }
  __syncthreads();

  if (kh == 0) {
    As[hp][lane]       = (256.f * a0 + sumC + (s0l + s0h) + PB[hp][lane])       * (1.f / 512.f);
    As[hp][64 + lane]  = (256.f * a1 + sumC + (s1l + s1h) + PB[hp][64 + lane])  * (1.f / 512.f);
    As[hp][128 + lane] = (256.f * a2 + sumC + (s2l + s2h) + PB[hp][128 + lane]) * (1.f / 512.f);
    As[hp][192 + lane] = (256.f * a3 + sumC + (s3l + s3h) + PB[hp][192 + lane]) * (1.f / 512.f);
  }
  __syncthreads();

  // ---- phase 3: pack row m=tid into kB fragment layout (r8-verified)
  if (tid < 256) {
    const int fr2 = tid & 15, T = tid >> 4;
    uint4 o = make_uint4(cvt_pk(As[0][tid], As[1][tid]), cvt_pk(As[2][tid], As[3][tid]),
                         cvt_pk(As[4][tid], As[5][tid]), cvt_pk(As[6][tid], As[7][tid]));
    mf[((size_t)(b * 16 + T) * 4 + (hc >> 2)) * 64 + (hc & 3) * 16 + fr2] = o;
  }
}

// ---------------------------------------------------------------------------
// kB: out[m][d] = mh[m,:]@W2[:,d] + b2[d] + x[m][d].  A = mf fragments,
// B gather-cast from native W2 f32 (r6-proven). Wave = (m-tile, d-group).
// Grid (256, 4) = 1024 blocks x 256 thr -> 16 waves/CU.
// ---------------------------------------------------------------------------
__global__ __launch_bounds__(256) void kB(
    const uint4* __restrict__ mf, const float* __restrict__ W2,
    const float* __restrict__ b2, const float* __restrict__ x,
    float* __restrict__ out)
{
  const int tid = threadIdx.x, lane = tid & 63, wu = tid >> 6;
  const int mt = blockIdx.x;             // 0..255
  const int dg = blockIdx.y * 4 + wu;    // 0..15
  const int fr = lane & 15, fq = lane >> 4;

  const float* __restrict__ w2p = W2 + dg * 16 + fr;
  FragU bfr[4];
#pragma unroll
  for (int c = 0; c < 4; ++c) {
    float v[8];
#pragma unroll
    for (int j = 0; j < 8; ++j) v[j] = w2p[(size_t)(c * 32 + fq * 8 + j) * 256];
    bfr[c].q = make_uint4(cvt_pk(v[0], v[1]), cvt_pk(v[2], v[3]),
                          cvt_pk(v[4], v[5]), cvt_pk(v[6], v[7]));
  }

  f32x4 acc = {0.f, 0.f, 0.f, 0.f};
#pragma unroll
  for (int c = 0; c < 4; ++c) {
    FragU a;
    a.q = mf[((size_t)mt * 4 + c) * 64 + lane];
    acc = __builtin_amdgcn_mfma_f32_16x16x32_bf16(a.h, bfr[c].h, acc, 0, 0, 0);
  }

  const int d = dg * 16 + fr;
  const float bv = b2[d];
#pragma unroll
  for (int g = 0; g < 4; ++g) {
    const int m = mt * 16 + fq * 4 + g;
    const size_t o = (size_t)m * 256 + d;
    out[o] = acc[g] + bv + x[o];
  }
}

extern "C" void kernel_launch(void* const* d_in, const int* in_sizes, int n_in,
                              void* d_out, int out_size, void* d_ws, size_t ws_size,
                              hipStream_t stream) {
  const float* x  = (const float*)d_in[0];
  const float* W1 = (const float*)d_in[1];
  const float* b1 = (const float*)d_in[2];
  const float* W2 = (const float*)d_in[3];
  const float* b2 = (const float*)d_in[4];
  float* out = (float*)d_out;

  uint4* mf = (uint4*)d_ws;   // 65536 units = 1 MB (mh in kB fragment layout)

  kA<<<dim3(16, 16), 1024, 0, stream>>>(x, W1, b1, mf);
  kB<<<dim3(256, 4), 256, 0, stream>>>(mf, W2, b2, x, out);
}